// Round 8
// baseline (315.551 us; speedup 1.0000x reference)
//
#include <hip/hip_runtime.h>
#include <math.h>

// Problem dims
#define AA 256
#define HH 1024
#define CC 1024
#define NN 8192
#define MM 4096

// ws layout (float offsets).
#define WS_G      0
#define WS_GAMMA  1
#define GI_OFF    4
#define GH_OFF    (GI_OFF + 3*CC)          // 3076
#define WN_OFF    (GH_OFF + 3*CC)          // 6148: normalized read weights (8192)
#define P_OFF     (WN_OFF + NN)            // 14340; partials: 512 x 4096 floats = 8 MB

// Native vector type for __builtin_nontemporal_load (HIP's float4 is a class
// type the builtin rejects; this lowers to the same global_load_dwordx4 + nt).
typedef float nt_f4 __attribute__((ext_vector_type(4)));

__device__ __forceinline__ float wave_reduce(float v) {
    #pragma unroll
    for (int o = 32; o > 0; o >>= 1) v += __shfl_down(v, o);
    return v;
}

// K1: gi[row] = dot(x, W_ih[row]) + b_ih; gh[row] = dot(h_prev, W_hh[row]) + b_hh.
// Wave-per-row: 768 blocks x 256 threads (4 waves = 4 rows/block). 9 independent
// float4 loads per lane, shuffle-only reduce, no LDS. (Unchanged since R2 - known good.)
__global__ __launch_bounds__(256) void k_gru_gates(
    const float* __restrict__ action, const float* __restrict__ hidden,
    const float* __restrict__ W_ih, const float* __restrict__ W_hh,
    const float* __restrict__ b_ih, const float* __restrict__ b_hh,
    const float* __restrict__ hprev, float* __restrict__ ws)
{
    const int t = threadIdx.x;
    const int wid = t >> 6, lane = t & 63;
    const int row = blockIdx.x * 4 + wid;

    const float4* __restrict__ Wih4 = (const float4*)W_ih + (size_t)row * 320; // 1280/4
    const float4* __restrict__ Whh4 = (const float4*)W_hh + (size_t)row * 256; // 1024/4
    const float4* __restrict__ act4 = (const float4*)action;  // 64 float4
    const float4* __restrict__ hid4 = (const float4*)hidden;  // 256 float4
    const float4* __restrict__ hp4  = (const float4*)hprev;   // 256 float4

    float4 a[5], b[4], xa[5], xb[4];
    #pragma unroll
    for (int j = 0; j < 5; ++j) a[j] = Wih4[lane + 64 * j];
    #pragma unroll
    for (int j = 0; j < 4; ++j) b[j] = Whh4[lane + 64 * j];
    xa[0] = act4[lane];
    #pragma unroll
    for (int j = 1; j < 5; ++j) xa[j] = hid4[lane + 64 * (j - 1)];
    #pragma unroll
    for (int j = 0; j < 4; ++j) xb[j] = hp4[lane + 64 * j];

    float si = 0.0f, sh = 0.0f;
    #pragma unroll
    for (int j = 0; j < 5; ++j)
        si += a[j].x * xa[j].x + a[j].y * xa[j].y + a[j].z * xa[j].z + a[j].w * xa[j].w;
    #pragma unroll
    for (int j = 0; j < 4; ++j)
        sh += b[j].x * xb[j].x + b[j].y * xb[j].y + b[j].z * xb[j].z + b[j].w * xb[j].w;

    si = wave_reduce(si);
    sh = wave_reduce(sh);
    if (lane == 0) {
        ws[GI_OFF + row] = si + b_ih[row];
        ws[GH_OFF + row] = sh + b_hh[row];
    }
}

// K2 (1 block, 1024 threads): GRU combine -> h -> hidden output; g = sigmoid(h.W_gate+b),
// gamma = softplus(h.W_gamma+b); then the ENTIRE weight path in-block (no atomics):
// t_i = (g + (1-g)*prev_i)^gamma  [cosine-sim weights are identically 1.0: softmax over a
// size-1 axis; circular-conv scalar cancels in sharpen], S = block-reduce(t),
// weight outputs = t/S written directly to d_out, normalized read weights to ws for K3.
// (Unchanged from R7 - known good.)
__global__ __launch_bounds__(1024) void k_gru_combine(
    const float* __restrict__ hprev,
    const float* __restrict__ prev_r, const float* __restrict__ prev_w,
    const float* __restrict__ W_gate, const float* __restrict__ b_gate,
    const float* __restrict__ W_gamma, const float* __restrict__ b_gamma,
    float* __restrict__ ws, float* __restrict__ d_out)
{
    const int c = threadIdx.x;
    __shared__ float rg[16], rm[16], bc[4];

    // ---- GRU combine ----
    const float* gi = ws + GI_OFF;
    const float* gh = ws + GH_OFF;
    const float r = 1.0f / (1.0f + expf(-(gi[c] + gh[c])));
    const float z = 1.0f / (1.0f + expf(-(gi[CC + c] + gh[CC + c])));
    const float n = tanhf(gi[2 * CC + c] + r * gh[2 * CC + c]);
    const float h = (1.0f - z) * n + z * hprev[c];
    d_out[MM + 2 * NN + c] = h;   // new_controller_hidden section

    // ---- g, gamma ----
    float vg = wave_reduce(h * W_gate[c]);
    float vm = wave_reduce(h * W_gamma[c]);
    const int wid = c >> 6;
    if ((c & 63) == 0) { rg[wid] = vg; rm[wid] = vm; }
    __syncthreads();
    if (c == 0) {
        float sg = 0.0f, sm = 0.0f;
        #pragma unroll
        for (int i = 0; i < 16; ++i) { sg += rg[i]; sm += rm[i]; }
        sg += b_gate[0];
        sm += b_gamma[0];
        const float g = 1.0f / (1.0f + expf(-sg));
        const float gamma = (sm > 20.0f) ? sm : log1pf(expf(sm));
        ws[WS_G] = g; ws[WS_GAMMA] = gamma;
        bc[0] = g; bc[1] = gamma;
    }
    __syncthreads();
    const float g = bc[0], gamma = bc[1];

    // ---- weights: 8 rows per thread, coalesced (row = c + 1024*k) ----
    float tr[8], tw[8];
    float sr = 0.0f, sw = 0.0f;
    #pragma unroll
    for (int k = 0; k < 8; ++k) {
        const int row = c + 1024 * k;
        tr[k] = powf(g + (1.0f - g) * prev_r[row], gamma);
        tw[k] = powf(g + (1.0f - g) * prev_w[row], gamma);
        sr += tr[k]; sw += tw[k];
    }
    sr = wave_reduce(sr);
    sw = wave_reduce(sw);
    if ((c & 63) == 0) { rg[wid] = sr; rm[wid] = sw; }
    __syncthreads();
    if (c == 0) {
        float a = 0.0f, b = 0.0f;
        #pragma unroll
        for (int i = 0; i < 16; ++i) { a += rg[i]; b += rm[i]; }
        bc[2] = 1.0f / a;   // 1/S_r
        bc[3] = 1.0f / b;   // 1/S_w
    }
    __syncthreads();
    const float isr = bc[2], isw = bc[3];
    #pragma unroll
    for (int k = 0; k < 8; ++k) {
        const int row = c + 1024 * k;
        const float wr = tr[k] * isr;
        ws[WN_OFF + row]     = wr;             // normalized, for K3
        d_out[MM + row]      = wr;             // read_weight output
        d_out[MM + NN + row] = tw[k] * isw;    // write_weight output
    }
}

// K3: the 128 MB pass -- CHANNEL-UNIFORM layout. 512 blocks; block b reads 16
// CONTIGUOUS rows = one 256 KB sequential span (per instruction the block covers
// 4 KB contiguous; addr/4KB walks consecutive integers -> all HBM channels hit
// uniformly). The old column-block layout touched only addr/4KB = 4*row -> 1/4
// of channels at 4x traffic, which is why every ILP/occupancy variant pinned at
// ~1.7 TB/s (= peak/4). Thread t owns f4-cols {t, t+256, t+512, t+768}; 2 rows
// x 4 quarters = 8 nt loads in flight; 4 float4 accumulators.
__global__ __launch_bounds__(256) void k_readvec(
    const float* __restrict__ memory, float* __restrict__ ws)
{
    __shared__ float tch[16];
    const int t = threadIdx.x;
    const int b = blockIdx.x;       // 0..511
    const int row0 = b * 16;

    if (t < 16) tch[t] = ws[WN_OFF + row0 + t];
    __syncthreads();

    const nt_f4* __restrict__ mem4 = (const nt_f4*)memory + (size_t)row0 * 1024 + t;
    float ac[4][4];
    #pragma unroll
    for (int q = 0; q < 4; ++q)
        ac[q][0] = ac[q][1] = ac[q][2] = ac[q][3] = 0.0f;

    #pragma unroll
    for (int rp = 0; rp < 8; ++rp) {            // 2 rows / iter, 8 loads in flight
        nt_f4 m[2][4];
        #pragma unroll
        for (int r2 = 0; r2 < 2; ++r2)
            #pragma unroll
            for (int q = 0; q < 4; ++q)
                m[r2][q] = __builtin_nontemporal_load(
                    &mem4[(size_t)(rp * 2 + r2) * 1024 + q * 256]);
        #pragma unroll
        for (int r2 = 0; r2 < 2; ++r2) {
            const float w = tch[rp * 2 + r2];
            #pragma unroll
            for (int q = 0; q < 4; ++q) {
                ac[q][0] += w * m[r2][q].x;
                ac[q][1] += w * m[r2][q].y;
                ac[q][2] += w * m[r2][q].z;
                ac[q][3] += w * m[r2][q].w;
            }
        }
    }
    float4* __restrict__ P4 = (float4*)(ws + P_OFF) + (size_t)b * 1024 + t;
    #pragma unroll
    for (int q = 0; q < 4; ++q) {
        float4 o; o.x = ac[q][0]; o.y = ac[q][1]; o.z = ac[q][2]; o.w = ac[q][3];
        P4[q * 256] = o;
    }
}

// K4: reduce 512 partials -> read_vector. 64 blocks; block rb owns f4-cols
// [rb*16,+16). Thread (col = t&15, rg = t>>4): sum 32 partial rows; LDS reduce
// over 16 row-groups. No division -- weights were pre-normalized.
__global__ __launch_bounds__(256) void k_finalize(
    const float* __restrict__ ws, float* __restrict__ d_out)
{
    __shared__ float4 red[256];
    const int t = threadIdx.x, rb = blockIdx.x;
    const int col = t & 15;
    const int rg  = t >> 4;
    const int c4  = rb * 16 + col;              // 0..1023
    const float4* __restrict__ P4 = (const float4*)(ws + P_OFF);
    float4 s = {0.0f, 0.0f, 0.0f, 0.0f};
    #pragma unroll 8
    for (int k = 0; k < 32; ++k) {
        float4 v = P4[(size_t)(rg * 32 + k) * 1024 + c4];
        s.x += v.x; s.y += v.y; s.z += v.z; s.w += v.w;
    }
    red[t] = s;
    __syncthreads();
    if (t < 16) {
        float4 a = red[t];
        #pragma unroll
        for (int g2 = 1; g2 < 16; ++g2) {
            float4 v = red[g2 * 16 + t];
            a.x += v.x; a.y += v.y; a.z += v.z; a.w += v.w;
        }
        ((float4*)d_out)[rb * 16 + t] = a;      // read_vector
    }
}

extern "C" void kernel_launch(void* const* d_in, const int* in_sizes, int n_in,
                              void* d_out, int out_size, void* d_ws, size_t ws_size,
                              hipStream_t stream)
{
    const float* action = (const float*)d_in[0];
    const float* hidden = (const float*)d_in[1];
    const float* prev_r = (const float*)d_in[2];
    const float* prev_w = (const float*)d_in[3];
    const float* hprev  = (const float*)d_in[4];   // prev_controller_hidden
    const float* memory = (const float*)d_in[5];
    const float* W_ih   = (const float*)d_in[6];
    const float* W_hh   = (const float*)d_in[7];
    const float* b_ih   = (const float*)d_in[8];
    const float* b_hh   = (const float*)d_in[9];
    // d_in[10..19] provably unused: softmax over size-1 axis == 1 (kills W_read/W_write
    // and the memory-norm pass), circular-conv scalar cancels in sharpen (kills W_shift),
    // memory write is discarded (kills W_add/W_erase).
    const float* W_gamma = (const float*)d_in[20];
    const float* b_gamma = (const float*)d_in[21];
    const float* W_gate  = (const float*)d_in[22];
    const float* b_gate  = (const float*)d_in[23];

    float* ws  = (float*)d_ws;
    float* out = (float*)d_out;

    hipLaunchKernelGGL(k_gru_gates, dim3(3 * CC / 4), dim3(256), 0, stream,
                       action, hidden, W_ih, W_hh, b_ih, b_hh, hprev, ws);
    hipLaunchKernelGGL(k_gru_combine, dim3(1), dim3(1024), 0, stream,
                       hprev, prev_r, prev_w, W_gate, b_gate, W_gamma, b_gamma, ws, out);
    hipLaunchKernelGGL(k_readvec, dim3(512), dim3(256), 0, stream,
                       memory, ws);
    hipLaunchKernelGGL(k_finalize, dim3(64), dim3(256), 0, stream,
                       ws, out);
}